// Round 18
// baseline (229.241 us; speedup 1.0000x reference)
//
#include <hip/hip_runtime.h>
#include <hip/hip_fp16.h>
#include <math.h>

#define HH 512
#define WW 512
#define BB 32
#define CHUNK 32

typedef unsigned u32;

#define NEG_INF2 0xFC00FC00u
#define POS_INF2 0x7C007C00u

// Packed f16 ops via inline asm (ROCm 7.2 headers lack __hmin2/__hmax2).
__device__ __forceinline__ u32 pkmin(u32 a, u32 b) {
    u32 r; asm("v_pk_min_f16 %0, %1, %2" : "=v"(r) : "v"(a), "v"(b)); return r;
}
__device__ __forceinline__ u32 pkmax(u32 a, u32 b) {
    u32 r; asm("v_pk_max_f16 %0, %1, %2" : "=v"(r) : "v"(a), "v"(b)); return r;
}
__device__ __forceinline__ u32 pksub(u32 a, u32 b) {   // a - b, both halves
    u32 r; asm("v_pk_add_f16 %0, %1, %2 neg_lo:[0,1] neg_hi:[0,1]" : "=v"(r) : "v"(a), "v"(b)); return r;
}
__device__ __forceinline__ u32 min3p(u32 a, u32 b, u32 c) { return pkmin(pkmin(a, b), c); }
__device__ __forceinline__ u32 max3p(u32 a, u32 b, u32 c) { return pkmax(pkmax(a, b), c); }

// {lo: a.hi, hi: b.lo} — shift-by-one-element view between packed pairs.
__device__ __forceinline__ u32 shl1(u32 a, u32 b) {
    return __builtin_amdgcn_alignbit(b, a, 16);
}

union H2U { __half2 h; u32 u; };
__device__ __forceinline__ u32 f2toh2(float lo, float hi) {
    H2U t; t.h = __float22half2_rn(make_float2(lo, hi)); return t.u;
}
__device__ __forceinline__ float2 h2tof2(u32 v) {
    H2U t; t.u = v; return __half22float2(t.h);
}

// Row load for depth-T pipeline: T+1 uint2/float4 loads at even pair bases
// (always aligned), row clamped (wave-uniform), OOB pairs forced +inf
// (= reference pad; pair-aligned so no partial masks).
template <int T, int F32>
__device__ __forceinline__ void loadrowT(const float* __restrict__ imgF,
                                         const unsigned short* __restrict__ imgH,
                                         int R, const int (&pb)[T + 1],
                                         const bool (&cXL)[2 * T + 2],
                                         const bool (&cXR)[2 * T + 2],
                                         u32 (&X)[2 * T + 2]) {
    const int Rc = R < 0 ? 0 : (R > HH - 1 ? HH - 1 : R);
    if (F32) {
        const float* rb = imgF + (size_t)Rc * WW;
        #pragma unroll
        for (int m = 0; m <= T; ++m) {
            float4 v = *(const float4*)(rb + 2 * pb[m]);
            X[2 * m] = f2toh2(v.x, v.y); X[2 * m + 1] = f2toh2(v.z, v.w);
        }
    } else {
        const unsigned short* rb = imgH + (size_t)Rc * WW;
        #pragma unroll
        for (int m = 0; m <= T; ++m) {
            uint2 v = *(const uint2*)(rb + 2 * pb[m]);
            X[2 * m] = v.x; X[2 * m + 1] = v.y;
        }
    }
    #pragma unroll
    for (int j = 0; j < T; ++j) X[j] = cXL[j] ? POS_INF2 : X[j];
    #pragma unroll
    for (int j = T + 2; j < 2 * T + 2; ++j) X[j] = cXR[j] ? POS_INF2 : X[j];
}

// One row of the depth-T pipeline (T fused skeleton iterations).
// Stage k: input x_k window WX = 2+2(T-k) pairs; hm (horiz min3) -> mn
// (vert min3 + OOB -inf masks) -> hx (horiz max3) -> x_{k+1} = relu(x -
// relu(maxpool - mn)) + OOB +inf masks. Ring roles alternate via caller.
// Masks use 8 hoisted per-lane conds: clv[d]=(pl<d), crv[v]=(pl>255-v).
template <int T, int SRCF32, int FUSED>
__device__ __forceinline__ void rowstepT(
    const float* __restrict__ imgF, const unsigned short* __restrict__ imgH,
    const float* __restrict__ cmp, unsigned short* __restrict__ outp,
    float& acc0, float& acc1,
    int R, int gx0, bool doStore,
    const int (&pb)[T + 1],
    const bool (&cXL)[2 * T + 2], const bool (&cXR)[2 * T + 2],
    const bool (&clv)[T + 2], const bool (&crv)[T + 3],
    const u32 (&Xin)[2 * T + 2], u32 (&XL)[2 * T + 2],
    u32 (&hmO)[T][2 * T + 2], u32 (&hmN)[T][2 * T + 2],
    u32 (&mnp)[T][2 * T],
    u32 (&hxO)[T][2 * T], u32 (&hxN)[T][2 * T],
    u32 (&xO)[T][2 * T], u32 (&xN)[T][2 * T],
    float4& cqC, float4& cqL) {
    // prefetch row R+3 into the dead slot
    loadrowT<T, SRCF32>(imgF, imgH, R + 3, pb, cXL, cXR, XL);

    float4 cmpCur;
    if (FUSED) {
        cmpCur = cqC;
        int Rc = R - 1;
        Rc = Rc < 0 ? 0 : (Rc > HH - 1 ? HH - 1 : Rc);
        cqL = *(const float4*)(cmp + (size_t)Rc * WW + gx0);
    }

    u32 cur[2 * T + 2];
    #pragma unroll
    for (int j = 0; j < 2 * T + 2; ++j) cur[j] = Xin[j];

    #pragma unroll
    for (int k = 0; k < T; ++k) {
        const int WX = 2 + 2 * (T - k);
        // horizontal min3 (edge halves garbage, unconsumed or masked)
        u32 L[2 * T + 3];
        L[0] = shl1(cur[0], cur[0]);
        #pragma unroll
        for (int j = 1; j < WX; ++j) L[j] = shl1(cur[j - 1], cur[j]);
        L[WX] = shl1(cur[WX - 1], cur[WX - 1]);
        u32 hm[2 * T + 2];
        #pragma unroll
        for (int j = 0; j < WX; ++j) hm[j] = min3p(L[j], cur[j], L[j + 1]);
        // vertical min3 -> mn (row R-(2k+1))
        u32 M[2 * T + 2];
        #pragma unroll
        for (int j = 0; j < WX; ++j) M[j] = min3p(hmO[k][j], hmN[k][j], hm[j]);
        if (!((unsigned)(R - (2 * k + 1)) < HH)) {      // wave-uniform, rare
            #pragma unroll
            for (int j = 0; j < WX; ++j) M[j] = NEG_INF2;
        }
        #pragma unroll
        for (int j = 0; j < WX; ++j) {
            if (j < T - k)      M[j] = clv[(T - k) - j] ? NEG_INF2 : M[j];
            if (j >= T - k + 2) M[j] = crv[j - (T - k)] ? NEG_INF2 : M[j];
        }
        // horizontal max3 of mn
        u32 ML[2 * T + 2];
        #pragma unroll
        for (int j = 1; j < WX; ++j) ML[j] = shl1(M[j - 1], M[j]);
        u32 hx[2 * T];
        #pragma unroll
        for (int j = 0; j < WX - 2; ++j) hx[j] = max3p(ML[j + 1], M[j + 1], ML[j + 2]);
        // x-update (row R-(2k+2))
        u32 xn[2 * T];
        #pragma unroll
        for (int j = 0; j < WX - 2; ++j) {
            u32 mp = max3p(hxO[k][j], hxN[k][j], hx[j]);
            u32 ct = pkmax(pksub(mp, mnp[k][j]), 0u);
            xn[j] = pkmax(pksub(xO[k][j], ct), 0u);
        }
        if (k < T - 1) {
            if (!((unsigned)(R - (2 * k + 2)) < HH)) {
                #pragma unroll
                for (int j = 0; j < WX - 2; ++j) xn[j] = POS_INF2;
            }
        }
        #pragma unroll
        for (int j = 0; j < WX - 2; ++j) {
            if (j <= T - k - 2) xn[j] = clv[(T - k) - j - 1] ? POS_INF2 : xn[j];
            if (j >= T - k + 1) xn[j] = crv[j + 1 - (T - k)] ? POS_INF2 : xn[j];
        }
        // rotate rings
        #pragma unroll
        for (int j = 0; j < WX; ++j) hmO[k][j] = hm[j];
        #pragma unroll
        for (int j = 0; j < WX - 2; ++j) {
            mnp[k][j] = M[j + 1]; hxO[k][j] = hx[j]; xO[k][j] = cur[j + 1];
        }
        if (k == T - 1) {
            if (doStore) {
                if (FUSED) {
                    float2 f0 = h2tof2(xn[0]);
                    float2 f1 = h2tof2(xn[1]);
                    acc0 += f0.x * cmpCur.x + f0.y * cmpCur.y + f1.x * cmpCur.z + f1.y * cmpCur.w;
                    acc1 += f0.x + f0.y + f1.x + f1.y;
                } else {
                    uint2 ov; ov.x = xn[0]; ov.y = xn[1];
                    *(uint2*)(outp + (size_t)(R - 2 * T) * WW + gx0) = ov;
                }
            }
        } else {
            #pragma unroll
            for (int j = 0; j < WX - 2; ++j) cur[j] = xn[j];
        }
    }
}

// T fused soft-skeletonize iterations per pass, packed-f16, no LDS,
// 4-row rotated loop body (zero cross-iteration movs), depth-3 prefetch.
// Round-17 lesson: per-pass time ~ bytes/2.5TB/s regardless of compute/
// occupancy/scheduling -> cut PASSES: 10 iters = T4 + T4 + T2(fused),
// 3 dispatches, 256 MB total vs 384.
template <int T, int SRCF32, int FUSED>
__global__ __launch_bounds__(256) void skelT(const float* __restrict__ sfA,
                                             const float* __restrict__ sfB,
                                             const unsigned short* __restrict__ shA,
                                             const unsigned short* __restrict__ shB,
                                             const float* __restrict__ cmpA,
                                             const float* __restrict__ cmpB,
                                             unsigned short* __restrict__ dst,
                                             float* __restrict__ partials) {
    constexpr int NX = 2 * T + 2;
    const int s = blockIdx.x * 64 + threadIdx.x;            // span 0..127
    const int y0 = (blockIdx.y * 4 + threadIdx.y) * CHUNK;  // output row start
    const int z = blockIdx.z;
    const float* imgF = nullptr;
    const unsigned short* imgH = nullptr;
    if (SRCF32) imgF = (z < BB) ? (sfA + (size_t)z * (HH * WW))
                                : (sfB + (size_t)(z - BB) * (HH * WW));
    else        imgH = (z < BB) ? (shA + (size_t)z * (HH * WW))
                                : (shB + (size_t)(z - BB) * (HH * WW));
    const float* cmp = nullptr;
    if (FUSED) cmp = (z < BB) ? (cmpA + (size_t)z * (HH * WW))
                              : (cmpB + (size_t)(z - BB) * (HH * WW));
    unsigned short* outp = FUSED ? nullptr : (dst + (size_t)z * (HH * WW));
    const int gx0 = 4 * s;
    const int pl = 2 * s;                                   // own abs pair

    // clamped even pair bases for the T+1 row loads
    int pb[T + 1];
    #pragma unroll
    for (int m = 0; m <= T; ++m) {
        int b = pl - T + 2 * m;
        pb[m] = b < 0 ? 0 : (b > 254 ? 254 : b);
    }
    // per-lane boundary conds (hoisted; become SGPR lane-masks)
    bool cXL[NX], cXR[NX];
    #pragma unroll
    for (int j = 0; j < NX; ++j) {
        cXL[j] = (pl - T + j) < 0;
        cXR[j] = (pl - T + j) > 255;
    }
    bool clv[T + 2], crv[T + 3];
    #pragma unroll
    for (int d = 0; d < T + 2; ++d) clv[d] = (pl < d);
    #pragma unroll
    for (int v = 0; v < T + 3; ++v) crv[v] = (pl > 255 - v);

    // ring state (unused high slots DCE'd via static unrolled indexing)
    u32 hmA[T][NX], hmB[T][NX];
    u32 mnp[T][NX - 2];
    u32 hxA[T][NX - 2], hxB[T][NX - 2];
    u32 xA_[T][NX - 2], xB_[T][NX - 2];
    #pragma unroll
    for (int k = 0; k < T; ++k) {
        const int WX = 2 + 2 * (T - k);
        #pragma unroll
        for (int j = 0; j < WX; ++j) { hmA[k][j] = POS_INF2; hmB[k][j] = POS_INF2; }
        #pragma unroll
        for (int j = 0; j < WX - 2; ++j) {
            mnp[k][j] = NEG_INF2;
            hxA[k][j] = NEG_INF2; hxB[k][j] = NEG_INF2;
            xA_[k][j] = POS_INF2; xB_[k][j] = POS_INF2;
        }
    }

    u32 xs0[NX], xs1[NX], xs2[NX], xs3[NX];
    float4 cq0, cq1, cq2, cq3;
    cq0.x = cq0.y = cq0.z = cq0.w = 0.f;
    cq1 = cq0; cq2 = cq0; cq3 = cq0;
    float acc0 = 0.0f, acc1 = 0.0f;

    const int R0 = y0 - 2 * T;
    loadrowT<T, SRCF32>(imgF, imgH, R0 + 0, pb, cXL, cXR, xs0);
    loadrowT<T, SRCF32>(imgF, imgH, R0 + 1, pb, cXL, cXR, xs1);
    loadrowT<T, SRCF32>(imgF, imgH, R0 + 2, pb, cXL, cXR, xs2);

    #pragma unroll 1
    for (int it = 0; it < (CHUNK + 4 * T) / 4; ++it) {
        const int Rb = R0 + 4 * it;
        const bool st = (it >= T);
        rowstepT<T, SRCF32, FUSED>(imgF, imgH, cmp, outp, acc0, acc1,
            Rb + 0, gx0, st, pb, cXL, cXR, clv, crv, xs0, xs3,
            hmA, hmB, mnp, hxA, hxB, xA_, xB_, cq0, cq3);
        rowstepT<T, SRCF32, FUSED>(imgF, imgH, cmp, outp, acc0, acc1,
            Rb + 1, gx0, st, pb, cXL, cXR, clv, crv, xs1, xs0,
            hmB, hmA, mnp, hxB, hxA, xB_, xA_, cq1, cq0);
        rowstepT<T, SRCF32, FUSED>(imgF, imgH, cmp, outp, acc0, acc1,
            Rb + 2, gx0, st, pb, cXL, cXR, clv, crv, xs2, xs1,
            hmA, hmB, mnp, hxA, hxB, xA_, xB_, cq2, cq1);
        rowstepT<T, SRCF32, FUSED>(imgF, imgH, cmp, outp, acc0, acc1,
            Rb + 3, gx0, st, pb, cXL, cXR, clv, crv, xs3, xs2,
            hmB, hmA, mnp, hxB, hxA, xB_, xA_, cq3, cq2);
    }

    if (FUSED) {
        for (int off = 32; off; off >>= 1) {
            acc0 += __shfl_down(acc0, off);
            acc1 += __shfl_down(acc1, off);
        }
        __shared__ float red[4][2];
        if (threadIdx.x == 0) { red[threadIdx.y][0] = acc0; red[threadIdx.y][1] = acc1; }
        __syncthreads();
        if (threadIdx.x == 0 && threadIdx.y == 0) {
            const int tile = blockIdx.x * gridDim.y + blockIdx.y;  // 0..7
            float* p = partials + ((size_t)z * 16 + tile) * 2;
            p[0] = red[0][0] + red[1][0] + red[2][0] + red[3][0];
            p[1] = red[0][1] + red[1][1] + red[2][1] + red[3][1];
        }
    }
}

// partials layout: [z][16 tile slots][2] (first ntiles used per z);
// z<32: (sum clp*tgt, sum clp); z>=32: (sum skt*prd, sum skt)
__global__ __launch_bounds__(64) void finalize2(const float* __restrict__ partials,
                                                int ntiles,
                                                float* __restrict__ out) {
    const int b = threadIdx.x;
    float iflat = 0.f, tflat = 0.f;
    if (b < BB) {
        float v0 = 0.f, v1 = 0.f, v2 = 0.f, v3 = 0.f;
        for (int t = 0; t < ntiles; ++t) {
            v0 += partials[((size_t)b * 16 + t) * 2 + 0];
            v1 += partials[((size_t)b * 16 + t) * 2 + 1];
            v2 += partials[((size_t)(b + BB) * 16 + t) * 2 + 0];
            v3 += partials[((size_t)(b + BB) * 16 + t) * 2 + 1];
        }
        iflat = (v0 + 1e-6f) / (v1 + 1e-6f);
        tflat = (v2 + 1e-6f) / (v3 + 1e-6f);
    }
    float prod = iflat * tflat;
    float ssum = iflat + tflat;
    for (int off = 32; off; off >>= 1) {
        prod += __shfl_down(prod, off);
        ssum += __shfl_down(ssum, off);
    }
    if (threadIdx.x == 0) out[0] = 1.0f - 2.0f * prod / ssum;
}

extern "C" void kernel_launch(void* const* d_in, const int* in_sizes, int n_in,
                              void* d_out, int out_size, void* d_ws, size_t ws_size,
                              hipStream_t stream) {
    const float* pred = (const float*)d_in[0];
    const float* target = (const float*)d_in[1];
    float* out = (float*)d_out;
    char* ws = (char*)d_ws;
    const size_t N = (size_t)HH * WW;
    const size_t HALF = (size_t)BB * N;                 // elements per 32-image half
    const size_t IMG16 = HALF * sizeof(unsigned short); // 16 MB (f16, 32 imgs)

    dim3 block(64, 4);
    const int nby = HH / (CHUNK * 4);                   // 4
    const int ntiles = 2 * nby;                         // 8

    if (ws_size >= 4 * IMG16 + (1 << 16)) {
        // z=64 path: both chains per dispatch; 10 iters = T4 -> T4 -> T2-fused
        unsigned short* A = (unsigned short*)ws;
        unsigned short* B = (unsigned short*)(ws + 2 * IMG16);
        float* partials = (float*)(ws + 4 * IMG16);     // 64*16*2 floats
        dim3 grid(2, nby, 2 * BB);
        skelT<4, 1, 0><<<grid, block, 0, stream>>>(pred, target, nullptr, nullptr,
                                                   nullptr, nullptr, A, nullptr);
        skelT<4, 0, 0><<<grid, block, 0, stream>>>(nullptr, nullptr, A, A + HALF,
                                                   nullptr, nullptr, B, nullptr);
        skelT<2, 0, 1><<<grid, block, 0, stream>>>(nullptr, nullptr, B, B + HALF,
                                                   target, pred, nullptr, partials);
        finalize2<<<1, 64, 0, stream>>>(partials, ntiles, out);
    } else {
        // fallback: z=32 path with 2x16MB f16 buffers, per-chain T4/T4/T2
        unsigned short* b0 = (unsigned short*)ws;
        unsigned short* b1 = (unsigned short*)(ws + IMG16);
        float* partials = (float*)(ws + 2 * IMG16);
        dim3 grid(2, nby, BB);
        skelT<4, 1, 0><<<grid, block, 0, stream>>>(pred, pred, nullptr, nullptr,
                                                   nullptr, nullptr, b0, nullptr);
        skelT<4, 0, 0><<<grid, block, 0, stream>>>(nullptr, nullptr, b0, b0,
                                                   nullptr, nullptr, b1, nullptr);
        skelT<2, 0, 1><<<grid, block, 0, stream>>>(nullptr, nullptr, b1, b1,
                                                   target, target, nullptr, partials);
        skelT<4, 1, 0><<<grid, block, 0, stream>>>(target, target, nullptr, nullptr,
                                                   nullptr, nullptr, b0, nullptr);
        skelT<4, 0, 0><<<grid, block, 0, stream>>>(nullptr, nullptr, b0, b0,
                                                   nullptr, nullptr, b1, nullptr);
        skelT<2, 0, 1><<<grid, block, 0, stream>>>(nullptr, nullptr, b1, b1,
                                                   pred, pred, nullptr,
                                                   partials + (size_t)BB * 16 * 2);
        finalize2<<<1, 64, 0, stream>>>(partials, ntiles, out);
    }
}

// Round 19
// 170.643 us; speedup vs baseline: 1.3434x; 1.3434x over previous
//
#include <hip/hip_runtime.h>
#include <hip/hip_fp16.h>
#include <math.h>

#define HH 512
#define WW 512
#define BB 32
#define CHUNK 32

typedef unsigned u32;

#define NEG_INF2 0xFC00FC00u
#define POS_INF2 0x7C007C00u

__device__ __forceinline__ u32 pkmin(u32 a, u32 b) {
    u32 r; asm("v_pk_min_f16 %0, %1, %2" : "=v"(r) : "v"(a), "v"(b)); return r;
}
__device__ __forceinline__ u32 pkmax(u32 a, u32 b) {
    u32 r; asm("v_pk_max_f16 %0, %1, %2" : "=v"(r) : "v"(a), "v"(b)); return r;
}
__device__ __forceinline__ u32 pksub(u32 a, u32 b) {
    u32 r; asm("v_pk_add_f16 %0, %1, %2 neg_lo:[0,1] neg_hi:[0,1]" : "=v"(r) : "v"(a), "v"(b)); return r;
}
__device__ __forceinline__ u32 min3p(u32 a, u32 b, u32 c) { return pkmin(pkmin(a, b), c); }
__device__ __forceinline__ u32 max3p(u32 a, u32 b, u32 c) { return pkmax(pkmax(a, b), c); }
__device__ __forceinline__ u32 shl1(u32 a, u32 b) {
    return __builtin_amdgcn_alignbit(b, a, 16);
}

union H2U { __half2 h; u32 u; };
__device__ __forceinline__ u32 f2toh2(float lo, float hi) {
    H2U t; t.h = __float22half2_rn(make_float2(lo, hi)); return t.u;
}
__device__ __forceinline__ float2 h2tof2(u32 v) {
    H2U t; t.u = v; return __half22float2(t.h);
}

// ============================ T2 (r15-proven, verbatim) ============================
template <int F32>
__device__ __forceinline__ void loadrow6(const float* __restrict__ imgF,
                                         const unsigned short* __restrict__ imgH,
                                         int R, int cm4, int c0, int cp4,
                                         bool isL, bool isR, u32* X) {
    const int Rc = R < 0 ? 0 : (R > HH - 1 ? HH - 1 : R);
    if (F32) {
        const float* rb = imgF + (size_t)Rc * WW;
        float4 v0 = *(const float4*)(rb + cm4);
        float4 v1 = *(const float4*)(rb + c0);
        float4 v2 = *(const float4*)(rb + cp4);
        X[0] = f2toh2(v0.x, v0.y); X[1] = f2toh2(v0.z, v0.w);
        X[2] = f2toh2(v1.x, v1.y); X[3] = f2toh2(v1.z, v1.w);
        X[4] = f2toh2(v2.x, v2.y); X[5] = f2toh2(v2.z, v2.w);
    } else {
        const unsigned short* rb = imgH + (size_t)Rc * WW;
        uint2 a = *(const uint2*)(rb + cm4);
        uint2 b = *(const uint2*)(rb + c0);
        uint2 c = *(const uint2*)(rb + cp4);
        X[0] = a.x; X[1] = a.y; X[2] = b.x; X[3] = b.y; X[4] = c.x; X[5] = c.y;
    }
    u32 fl = __builtin_amdgcn_perm(X[0], X[1], 0x05040100u);
    X[1] = isL ? fl : X[1];
    u32 fr = __builtin_amdgcn_perm(X[4], X[3], 0x07060302u);
    X[4] = isR ? fr : X[4];
}

template <int SRCF32, int FUSED>
__device__ __forceinline__ void rowstep(
    const float* __restrict__ imgF, const unsigned short* __restrict__ imgH,
    const float* __restrict__ cmp, unsigned short* __restrict__ outp,
    float& acc0, float& acc1,
    int R, int cm4, int gx0, int cp4, bool isL, bool isR, bool doStore,
    u32 (&X)[6], u32 (&XL)[6],
    u32 (&hm0o)[6], u32 (&hm0n)[6], u32 (&mn0p)[4],
    u32 (&hx0o)[4], u32 (&hx0n)[4],
    u32 (&x0o)[4], u32 (&x0n)[4],
    u32 (&hm1o)[4], u32 (&hm1n)[4], u32 (&mn1p)[2],
    u32 (&hx1o)[2], u32 (&hx1n)[2],
    u32 (&x1o)[2], u32 (&x1n)[2],
    const u32 (&mk)[8],
    float4& cqC, float4& cqL) {
    loadrow6<SRCF32>(imgF, imgH, R + 3, cm4, gx0, cp4, isL, isR, XL);

    float4 cmpCur;
    if (FUSED) {
        cmpCur = cqC;
        int Rc = R - 1;
        Rc = Rc < 0 ? 0 : (Rc > HH - 1 ? HH - 1 : Rc);
        cqL = *(const float4*)(cmp + (size_t)Rc * WW + gx0);
    }

    u32 L[7];
    L[0] = shl1(X[0], X[0]);
    #pragma unroll
    for (int j = 1; j <= 5; ++j) L[j] = shl1(X[j - 1], X[j]);
    L[6] = shl1(X[5], X[5]);
    u32 hm0c[6];
    #pragma unroll
    for (int j = 0; j < 6; ++j) hm0c[j] = min3p(L[j], X[j], L[j + 1]);

    u32 M[6];
    #pragma unroll
    for (int j = 0; j < 6; ++j) M[j] = min3p(hm0o[j], hm0n[j], hm0c[j]);
    if (!((unsigned)(R - 1) < HH)) {
        #pragma unroll
        for (int j = 0; j < 6; ++j) M[j] = NEG_INF2;
    }
    M[0] = pkmin(M[0], mk[0]); M[1] = pkmin(M[1], mk[1]);
    M[4] = pkmin(M[4], mk[2]); M[5] = pkmin(M[5], mk[3]);

    u32 ML[6];
    #pragma unroll
    for (int j = 1; j <= 5; ++j) ML[j] = shl1(M[j - 1], M[j]);
    u32 hx0c[4];
    #pragma unroll
    for (int j = 0; j < 4; ++j) hx0c[j] = max3p(ML[j + 1], M[j + 1], ML[j + 2]);

    u32 x1c[4];
    #pragma unroll
    for (int j = 0; j < 4; ++j) {
        u32 mp = max3p(hx0o[j], hx0n[j], hx0c[j]);
        u32 ct = pkmax(pksub(mp, mn0p[j]), 0u);
        x1c[j] = pkmax(pksub(x0o[j], ct), 0u);
    }
    if (!((unsigned)(R - 2) < HH)) {
        #pragma unroll
        for (int j = 0; j < 4; ++j) x1c[j] = POS_INF2;
    }
    x1c[0] = pkmax(x1c[0], mk[4]);
    x1c[3] = pkmax(x1c[3], mk[5]);

    #pragma unroll
    for (int j = 0; j < 6; ++j) hm0o[j] = hm0c[j];
    #pragma unroll
    for (int j = 0; j < 4; ++j) { mn0p[j] = M[j + 1]; hx0o[j] = hx0c[j]; x0o[j] = X[j + 1]; }

    u32 XL1[5];
    XL1[0] = shl1(x1c[0], x1c[0]);
    #pragma unroll
    for (int j = 1; j <= 3; ++j) XL1[j] = shl1(x1c[j - 1], x1c[j]);
    XL1[4] = shl1(x1c[3], x1c[3]);
    u32 hm1c[4];
    #pragma unroll
    for (int j = 0; j < 4; ++j) hm1c[j] = min3p(XL1[j], x1c[j], XL1[j + 1]);

    u32 M1[4];
    #pragma unroll
    for (int j = 0; j < 4; ++j) M1[j] = min3p(hm1o[j], hm1n[j], hm1c[j]);
    if (!((unsigned)(R - 3) < HH)) {
        #pragma unroll
        for (int j = 0; j < 4; ++j) M1[j] = NEG_INF2;
    }
    M1[0] = pkmin(M1[0], mk[6]);
    M1[3] = pkmin(M1[3], mk[7]);

    u32 M1s[4];
    #pragma unroll
    for (int j = 1; j <= 3; ++j) M1s[j] = shl1(M1[j - 1], M1[j]);
    u32 hx1c[2];
    hx1c[0] = max3p(M1s[1], M1[1], M1s[2]);
    hx1c[1] = max3p(M1s[2], M1[2], M1s[3]);

    if (doStore) {
        u32 o[2];
        #pragma unroll
        for (int k = 0; k < 2; ++k) {
            u32 mp = max3p(hx1o[k], hx1n[k], hx1c[k]);
            u32 ct = pkmax(pksub(mp, mn1p[k]), 0u);
            o[k] = pkmax(pksub(x1o[k], ct), 0u);
        }
        if (FUSED) {
            float2 f0 = h2tof2(o[0]);
            float2 f1 = h2tof2(o[1]);
            acc0 += f0.x * cmpCur.x + f0.y * cmpCur.y + f1.x * cmpCur.z + f1.y * cmpCur.w;
            acc1 += f0.x + f0.y + f1.x + f1.y;
        } else {
            uint2 ov; ov.x = o[0]; ov.y = o[1];
            *(uint2*)(outp + (size_t)(R - 4) * WW + gx0) = ov;
        }
    }

    #pragma unroll
    for (int j = 0; j < 4; ++j) hm1o[j] = hm1c[j];
    mn1p[0] = M1[1]; mn1p[1] = M1[2];
    hx1o[0] = hx1c[0]; hx1o[1] = hx1c[1];
    x1o[0] = x1c[1]; x1o[1] = x1c[2];
}

template <int SRCF32, int FUSED>
__global__ __launch_bounds__(256) void skel2h_t(const float* __restrict__ sfA,
                                                const float* __restrict__ sfB,
                                                const unsigned short* __restrict__ shA,
                                                const unsigned short* __restrict__ shB,
                                                const float* __restrict__ cmpA,
                                                const float* __restrict__ cmpB,
                                                unsigned short* __restrict__ dst,
                                                float* __restrict__ partials) {
    const int s = blockIdx.x * 64 + threadIdx.x;
    const int y0 = (blockIdx.y * 4 + threadIdx.y) * CHUNK;
    const int z = blockIdx.z;
    const float* imgF = nullptr;
    const unsigned short* imgH = nullptr;
    if (SRCF32) imgF = (z < BB) ? (sfA + (size_t)z * (HH * WW))
                                : (sfB + (size_t)(z - BB) * (HH * WW));
    else        imgH = (z < BB) ? (shA + (size_t)z * (HH * WW))
                                : (shB + (size_t)(z - BB) * (HH * WW));
    const float* cmp = nullptr;
    if (FUSED) cmp = (z < BB) ? (cmpA + (size_t)z * (HH * WW))
                              : (cmpB + (size_t)(z - BB) * (HH * WW));
    unsigned short* outp = FUSED ? nullptr : (dst + (size_t)z * (HH * WW));
    const int gx0 = 4 * s;
    const bool isL = (s == 0), isR = (s == 127);
    const int cm4 = isL ? 0 : gx0 - 4;
    const int cp4 = isR ? gx0 : gx0 + 4;

    u32 mk[8];
    mk[0] = isL ? 0xFC007C00u : POS_INF2;
    mk[1] = isL ? NEG_INF2    : POS_INF2;
    mk[2] = isR ? NEG_INF2    : POS_INF2;
    mk[3] = isR ? 0x7C00FC00u : POS_INF2;
    mk[4] = isL ? POS_INF2    : NEG_INF2;
    mk[5] = isR ? POS_INF2    : NEG_INF2;
    mk[6] = isL ? 0xFC007C00u : POS_INF2;
    mk[7] = isR ? 0x7C00FC00u : POS_INF2;

    u32 hm0a[6], hm0b[6], mn0p[4];
    u32 hx0a[4], hx0b[4], x0a[4], x0b[4];
    u32 hm1a[4], hm1b[4], mn1p[2];
    u32 hx1a[2], hx1b[2], x1a[2], x1b[2];
    u32 xs0[6], xs1[6], xs2[6], xs3[6];
    float4 cq0, cq1, cq2, cq3;

    #pragma unroll
    for (int j = 0; j < 6; ++j) { hm0a[j] = POS_INF2; hm0b[j] = POS_INF2; }
    #pragma unroll
    for (int j = 0; j < 4; ++j) {
        mn0p[j] = NEG_INF2; hx0a[j] = NEG_INF2; hx0b[j] = NEG_INF2;
        x0a[j] = POS_INF2; x0b[j] = POS_INF2;
        hm1a[j] = POS_INF2; hm1b[j] = POS_INF2;
    }
    #pragma unroll
    for (int k = 0; k < 2; ++k) {
        mn1p[k] = NEG_INF2; hx1a[k] = NEG_INF2; hx1b[k] = NEG_INF2;
        x1a[k] = POS_INF2; x1b[k] = POS_INF2;
    }
    cq0.x = cq0.y = cq0.z = cq0.w = 0.f;
    cq1 = cq0; cq2 = cq0; cq3 = cq0;

    float acc0 = 0.0f, acc1 = 0.0f;

    loadrow6<SRCF32>(imgF, imgH, y0 - 4, cm4, gx0, cp4, isL, isR, xs0);
    loadrow6<SRCF32>(imgF, imgH, y0 - 3, cm4, gx0, cp4, isL, isR, xs1);
    loadrow6<SRCF32>(imgF, imgH, y0 - 2, cm4, gx0, cp4, isL, isR, xs2);

    #pragma unroll 1
    for (int it = 0; it < (CHUNK + 8) / 4; ++it) {
        const int Rb = y0 - 4 + 4 * it;
        const bool doStore = (it >= 2);
        rowstep<SRCF32, FUSED>(imgF, imgH, cmp, outp, acc0, acc1,
            Rb + 0, cm4, gx0, cp4, isL, isR, doStore,
            xs0, xs3, hm0a, hm0b, mn0p, hx0a, hx0b, x0a, x0b,
            hm1a, hm1b, mn1p, hx1a, hx1b, x1a, x1b, mk, cq0, cq3);
        rowstep<SRCF32, FUSED>(imgF, imgH, cmp, outp, acc0, acc1,
            Rb + 1, cm4, gx0, cp4, isL, isR, doStore,
            xs1, xs0, hm0b, hm0a, mn0p, hx0b, hx0a, x0b, x0a,
            hm1b, hm1a, mn1p, hx1b, hx1a, x1b, x1a, mk, cq1, cq0);
        rowstep<SRCF32, FUSED>(imgF, imgH, cmp, outp, acc0, acc1,
            Rb + 2, cm4, gx0, cp4, isL, isR, doStore,
            xs2, xs1, hm0a, hm0b, mn0p, hx0a, hx0b, x0a, x0b,
            hm1a, hm1b, mn1p, hx1a, hx1b, x1a, x1b, mk, cq2, cq1);
        rowstep<SRCF32, FUSED>(imgF, imgH, cmp, outp, acc0, acc1,
            Rb + 3, cm4, gx0, cp4, isL, isR, doStore,
            xs3, xs2, hm0b, hm0a, mn0p, hx0b, hx0a, x0b, x0a,
            hm1b, hm1a, mn1p, hx1b, hx1a, x1b, x1a, mk, cq3, cq2);
    }

    if (FUSED) {
        for (int off = 32; off; off >>= 1) {
            acc0 += __shfl_down(acc0, off);
            acc1 += __shfl_down(acc1, off);
        }
        __shared__ float red[4][2];
        if (threadIdx.x == 0) { red[threadIdx.y][0] = acc0; red[threadIdx.y][1] = acc1; }
        __syncthreads();
        if (threadIdx.x == 0 && threadIdx.y == 0) {
            const int tile = blockIdx.x * gridDim.y + blockIdx.y;
            float* p = partials + ((size_t)z * 16 + tile) * 2;
            p[0] = red[0][0] + red[1][0] + red[2][0] + red[3][0];
            p[1] = red[0][1] + red[1][1] + red[2][1] + red[3][1];
        }
    }
}

// ============================ T3 (hand-specialized, new) ============================
// Window: 10 pairs X[0..9] claiming pair indices pl-4..pl+5 (cols gx0-8..gx0+11),
// loaded via 5 aligned uint2/float4 at clamped even pair bases. OOB-claimed slots
// forced +inf via xm[8] (exact reference min-pool pad). Stage widths 8/6/4 pairs;
// stages 1,2 are r15's proven stage geometry (mask words mk[0..7] identical).
template <int F32>
__device__ __forceinline__ void loadrow10(const float* __restrict__ imgF,
                                          const unsigned short* __restrict__ imgH,
                                          int R, const int (&pb)[5],
                                          const u32 (&xm)[8], u32 (&X)[10]) {
    const int Rc = R < 0 ? 0 : (R > HH - 1 ? HH - 1 : R);
    if (F32) {
        const float* rb = imgF + (size_t)Rc * WW;
        #pragma unroll
        for (int m = 0; m < 5; ++m) {
            float4 v = *(const float4*)(rb + 2 * pb[m]);
            X[2 * m] = f2toh2(v.x, v.y); X[2 * m + 1] = f2toh2(v.z, v.w);
        }
    } else {
        const unsigned short* rb = imgH + (size_t)Rc * WW;
        #pragma unroll
        for (int m = 0; m < 5; ++m) {
            uint2 v = *(const uint2*)(rb + 2 * pb[m]);
            X[2 * m] = v.x; X[2 * m + 1] = v.y;
        }
    }
    X[0] = pkmax(X[0], xm[0]); X[1] = pkmax(X[1], xm[1]);
    X[2] = pkmax(X[2], xm[2]); X[3] = pkmax(X[3], xm[3]);
    X[6] = pkmax(X[6], xm[4]); X[7] = pkmax(X[7], xm[5]);
    X[8] = pkmax(X[8], xm[6]); X[9] = pkmax(X[9], xm[7]);
}

template <int SRCF32>
__device__ __forceinline__ void rowstep3(
    const float* __restrict__ imgF, const unsigned short* __restrict__ imgH,
    unsigned short* __restrict__ outp,
    int R, int gx0, bool doStore,
    const int (&pb)[5], const u32 (&xm)[8], const u32 (&m0)[6],
    const u32 (&x1m)[4], const u32 (&mk)[8],
    const u32 (&X)[10], u32 (&XL)[10],
    u32 (&hm0o)[8], u32 (&hm0n)[8], u32 (&mn0p)[6],
    u32 (&hx0o)[6], u32 (&hx0n)[6], u32 (&x0o)[6], u32 (&x0n)[6],
    u32 (&hm1o)[6], u32 (&hm1n)[6], u32 (&mn1p)[4],
    u32 (&hx1o)[4], u32 (&hx1n)[4], u32 (&x1o)[4], u32 (&x1n)[4],
    u32 (&hm2o)[4], u32 (&hm2n)[4], u32 (&mn2p)[2],
    u32 (&hx2o)[2], u32 (&hx2n)[2], u32 (&x2o)[2], u32 (&x2n)[2]) {
    loadrow10<SRCF32>(imgF, imgH, R + 3, pb, xm, XL);

    // ---- stage0: pairs 1..8, x-window X[0..9] ----
    u32 L[10];
    #pragma unroll
    for (int j = 1; j <= 9; ++j) L[j] = shl1(X[j - 1], X[j]);
    u32 hm0[8];
    #pragma unroll
    for (int a = 0; a < 8; ++a) hm0[a] = min3p(L[a + 1], X[a + 1], L[a + 2]);
    u32 M0[8];
    #pragma unroll
    for (int a = 0; a < 8; ++a) M0[a] = min3p(hm0o[a], hm0n[a], hm0[a]);
    if (!((unsigned)(R - 1) < HH)) {
        #pragma unroll
        for (int a = 0; a < 8; ++a) M0[a] = NEG_INF2;
    }
    M0[0] = pkmin(M0[0], m0[0]); M0[1] = pkmin(M0[1], m0[1]); M0[2] = pkmin(M0[2], m0[2]);
    M0[5] = pkmin(M0[5], m0[3]); M0[6] = pkmin(M0[6], m0[4]); M0[7] = pkmin(M0[7], m0[5]);
    u32 ML[8];
    #pragma unroll
    for (int a = 1; a <= 7; ++a) ML[a] = shl1(M0[a - 1], M0[a]);
    u32 hx0[6];
    #pragma unroll
    for (int b = 0; b < 6; ++b) hx0[b] = max3p(ML[b + 1], M0[b + 1], ML[b + 2]);
    u32 x1c[6];
    #pragma unroll
    for (int b = 0; b < 6; ++b) {
        u32 mp = max3p(hx0o[b], hx0n[b], hx0[b]);
        u32 ct = pkmax(pksub(mp, mn0p[b]), 0u);
        x1c[b] = pkmax(pksub(x0o[b], ct), 0u);
    }
    if (!((unsigned)(R - 2) < HH)) {
        #pragma unroll
        for (int b = 0; b < 6; ++b) x1c[b] = POS_INF2;
    }
    x1c[0] = pkmax(x1c[0], x1m[0]); x1c[1] = pkmax(x1c[1], x1m[1]);
    x1c[4] = pkmax(x1c[4], x1m[2]); x1c[5] = pkmax(x1c[5], x1m[3]);
    #pragma unroll
    for (int a = 0; a < 8; ++a) hm0o[a] = hm0[a];
    #pragma unroll
    for (int b = 0; b < 6; ++b) { mn0p[b] = M0[b + 1]; hx0o[b] = hx0[b]; x0o[b] = X[b + 2]; }

    // ---- stage1: 6-wide (r15 stage0 geometry) ----
    u32 L1[7];
    L1[0] = shl1(x1c[0], x1c[0]);
    #pragma unroll
    for (int j = 1; j <= 5; ++j) L1[j] = shl1(x1c[j - 1], x1c[j]);
    L1[6] = shl1(x1c[5], x1c[5]);
    u32 hm1[6];
    #pragma unroll
    for (int j = 0; j < 6; ++j) hm1[j] = min3p(L1[j], x1c[j], L1[j + 1]);
    u32 M1[6];
    #pragma unroll
    for (int j = 0; j < 6; ++j) M1[j] = min3p(hm1o[j], hm1n[j], hm1[j]);
    if (!((unsigned)(R - 3) < HH)) {
        #pragma unroll
        for (int j = 0; j < 6; ++j) M1[j] = NEG_INF2;
    }
    M1[0] = pkmin(M1[0], mk[0]); M1[1] = pkmin(M1[1], mk[1]);
    M1[4] = pkmin(M1[4], mk[2]); M1[5] = pkmin(M1[5], mk[3]);
    u32 ML1[6];
    #pragma unroll
    for (int j = 1; j <= 5; ++j) ML1[j] = shl1(M1[j - 1], M1[j]);
    u32 hx1[4];
    #pragma unroll
    for (int b = 0; b < 4; ++b) hx1[b] = max3p(ML1[b + 1], M1[b + 1], ML1[b + 2]);
    u32 x2c[4];
    #pragma unroll
    for (int b = 0; b < 4; ++b) {
        u32 mp = max3p(hx1o[b], hx1n[b], hx1[b]);
        u32 ct = pkmax(pksub(mp, mn1p[b]), 0u);
        x2c[b] = pkmax(pksub(x1o[b], ct), 0u);
    }
    if (!((unsigned)(R - 4) < HH)) {
        #pragma unroll
        for (int b = 0; b < 4; ++b) x2c[b] = POS_INF2;
    }
    x2c[0] = pkmax(x2c[0], mk[4]);
    x2c[3] = pkmax(x2c[3], mk[5]);
    #pragma unroll
    for (int j = 0; j < 6; ++j) hm1o[j] = hm1[j];
    #pragma unroll
    for (int b = 0; b < 4; ++b) { mn1p[b] = M1[b + 1]; hx1o[b] = hx1[b]; x1o[b] = x1c[b + 1]; }

    // ---- stage2: 4-wide (r15 stage1 geometry) ----
    u32 L2[5];
    L2[0] = shl1(x2c[0], x2c[0]);
    #pragma unroll
    for (int j = 1; j <= 3; ++j) L2[j] = shl1(x2c[j - 1], x2c[j]);
    L2[4] = shl1(x2c[3], x2c[3]);
    u32 hm2[4];
    #pragma unroll
    for (int j = 0; j < 4; ++j) hm2[j] = min3p(L2[j], x2c[j], L2[j + 1]);
    u32 M2[4];
    #pragma unroll
    for (int j = 0; j < 4; ++j) M2[j] = min3p(hm2o[j], hm2n[j], hm2[j]);
    if (!((unsigned)(R - 5) < HH)) {
        #pragma unroll
        for (int j = 0; j < 4; ++j) M2[j] = NEG_INF2;
    }
    M2[0] = pkmin(M2[0], mk[6]);
    M2[3] = pkmin(M2[3], mk[7]);
    u32 ML2[4];
    #pragma unroll
    for (int j = 1; j <= 3; ++j) ML2[j] = shl1(M2[j - 1], M2[j]);
    u32 hx2[2];
    hx2[0] = max3p(ML2[1], M2[1], ML2[2]);
    hx2[1] = max3p(ML2[2], M2[2], ML2[3]);
    if (doStore) {
        u32 o[2];
        #pragma unroll
        for (int k = 0; k < 2; ++k) {
            u32 mp = max3p(hx2o[k], hx2n[k], hx2[k]);
            u32 ct = pkmax(pksub(mp, mn2p[k]), 0u);
            o[k] = pkmax(pksub(x2o[k], ct), 0u);
        }
        uint2 ov; ov.x = o[0]; ov.y = o[1];
        *(uint2*)(outp + (size_t)(R - 6) * WW + gx0) = ov;
    }
    #pragma unroll
    for (int j = 0; j < 4; ++j) hm2o[j] = hm2[j];
    mn2p[0] = M2[1]; mn2p[1] = M2[2];
    hx2o[0] = hx2[0]; hx2o[1] = hx2[1];
    x2o[0] = x2c[1]; x2o[1] = x2c[2];
}

template <int SRCF32>
__global__ __launch_bounds__(256) void skel3h(const float* __restrict__ sfA,
                                              const float* __restrict__ sfB,
                                              const unsigned short* __restrict__ shA,
                                              const unsigned short* __restrict__ shB,
                                              unsigned short* __restrict__ dst) {
    const int s = blockIdx.x * 64 + threadIdx.x;
    const int y0 = (blockIdx.y * 4 + threadIdx.y) * CHUNK;
    const int z = blockIdx.z;
    const float* imgF = nullptr;
    const unsigned short* imgH = nullptr;
    if (SRCF32) imgF = (z < BB) ? (sfA + (size_t)z * (HH * WW))
                                : (sfB + (size_t)(z - BB) * (HH * WW));
    else        imgH = (z < BB) ? (shA + (size_t)z * (HH * WW))
                                : (shB + (size_t)(z - BB) * (HH * WW));
    unsigned short* outp = dst + (size_t)z * (HH * WW);
    const int gx0 = 4 * s;
    const int pl = 2 * s;
    const bool isL = (s == 0), isR = (s == 127);

    int pb[5];
    #pragma unroll
    for (int m = 0; m < 5; ++m) {
        int b = pl - 4 + 2 * m;
        pb[m] = b < 0 ? 0 : (b > 254 ? 254 : b);
    }
    // X-load +inf masks (identity = -inf for pkmax)
    u32 xm[8];
    xm[0] = (s <= 1)   ? POS_INF2 : NEG_INF2;   // X[0]
    xm[1] = (s <= 1)   ? POS_INF2 : NEG_INF2;   // X[1]
    xm[2] = (s == 0)   ? POS_INF2 : NEG_INF2;   // X[2]
    xm[3] = (s == 0)   ? POS_INF2 : NEG_INF2;   // X[3]
    xm[4] = (s == 127) ? POS_INF2 : NEG_INF2;   // X[6]
    xm[5] = (s == 127) ? POS_INF2 : NEG_INF2;   // X[7]
    xm[6] = (s >= 126) ? POS_INF2 : NEG_INF2;   // X[8]
    xm[7] = (s >= 126) ? POS_INF2 : NEG_INF2;   // X[9]
    // stage0 mn -inf masks (identity = +inf for pkmin)
    u32 m0[6];
    m0[0] = (s <= 1)   ? NEG_INF2 : POS_INF2;   // M0[0]
    m0[1] = (s == 0)   ? NEG_INF2 : POS_INF2;   // M0[1]
    m0[2] = (s == 0)   ? NEG_INF2 : POS_INF2;   // M0[2]
    m0[3] = (s == 127) ? NEG_INF2 : POS_INF2;   // M0[5]
    m0[4] = (s == 127) ? NEG_INF2 : POS_INF2;   // M0[6]
    m0[5] = (s >= 126) ? NEG_INF2 : POS_INF2;   // M0[7]
    // stage0 x1 +inf masks
    u32 x1m[4];
    x1m[0] = (s == 0)   ? POS_INF2 : NEG_INF2;  // x1[0]
    x1m[1] = (s == 0)   ? POS_INF2 : NEG_INF2;  // x1[1]
    x1m[2] = (s == 127) ? POS_INF2 : NEG_INF2;  // x1[4]
    x1m[3] = (s == 127) ? POS_INF2 : NEG_INF2;  // x1[5]
    // stages 1,2 masks (r15-proven geometry)
    u32 mk[8];
    mk[0] = isL ? 0xFC007C00u : POS_INF2;
    mk[1] = isL ? NEG_INF2    : POS_INF2;
    mk[2] = isR ? NEG_INF2    : POS_INF2;
    mk[3] = isR ? 0x7C00FC00u : POS_INF2;
    mk[4] = isL ? POS_INF2    : NEG_INF2;
    mk[5] = isR ? POS_INF2    : NEG_INF2;
    mk[6] = isL ? 0xFC007C00u : POS_INF2;
    mk[7] = isR ? 0x7C00FC00u : POS_INF2;

    u32 hm0a[8], hm0b[8], mn0p[6];
    u32 hx0a[6], hx0b[6], x0a[6], x0b[6];
    u32 hm1a[6], hm1b[6], mn1p[4];
    u32 hx1a[4], hx1b[4], x1a[4], x1b[4];
    u32 hm2a[4], hm2b[4], mn2p[2];
    u32 hx2a[2], hx2b[2], x2a[2], x2b[2];
    u32 xs0[10], xs1[10], xs2[10], xs3[10];

    #pragma unroll
    for (int j = 0; j < 8; ++j) { hm0a[j] = POS_INF2; hm0b[j] = POS_INF2; }
    #pragma unroll
    for (int j = 0; j < 6; ++j) {
        mn0p[j] = NEG_INF2; hx0a[j] = NEG_INF2; hx0b[j] = NEG_INF2;
        x0a[j] = POS_INF2; x0b[j] = POS_INF2;
        hm1a[j] = POS_INF2; hm1b[j] = POS_INF2;
    }
    #pragma unroll
    for (int j = 0; j < 4; ++j) {
        mn1p[j] = NEG_INF2; hx1a[j] = NEG_INF2; hx1b[j] = NEG_INF2;
        x1a[j] = POS_INF2; x1b[j] = POS_INF2;
        hm2a[j] = POS_INF2; hm2b[j] = POS_INF2;
    }
    #pragma unroll
    for (int k = 0; k < 2; ++k) {
        mn2p[k] = NEG_INF2; hx2a[k] = NEG_INF2; hx2b[k] = NEG_INF2;
        x2a[k] = POS_INF2; x2b[k] = POS_INF2;
    }

    const int R0 = y0 - 6;
    loadrow10<SRCF32>(imgF, imgH, R0 + 0, pb, xm, xs0);
    loadrow10<SRCF32>(imgF, imgH, R0 + 1, pb, xm, xs1);
    loadrow10<SRCF32>(imgF, imgH, R0 + 2, pb, xm, xs2);

    #pragma unroll 1
    for (int it = 0; it < (CHUNK + 12) / 4; ++it) {
        const int Rb = R0 + 4 * it;
        const bool st = (it >= 3);
        rowstep3<SRCF32>(imgF, imgH, outp, Rb + 0, gx0, st, pb, xm, m0, x1m, mk,
            xs0, xs3, hm0a, hm0b, mn0p, hx0a, hx0b, x0a, x0b,
            hm1a, hm1b, mn1p, hx1a, hx1b, x1a, x1b,
            hm2a, hm2b, mn2p, hx2a, hx2b, x2a, x2b);
        rowstep3<SRCF32>(imgF, imgH, outp, Rb + 1, gx0, st, pb, xm, m0, x1m, mk,
            xs1, xs0, hm0b, hm0a, mn0p, hx0b, hx0a, x0b, x0a,
            hm1b, hm1a, mn1p, hx1b, hx1a, x1b, x1a,
            hm2b, hm2a, mn2p, hx2b, hx2a, x2b, x2a);
        rowstep3<SRCF32>(imgF, imgH, outp, Rb + 2, gx0, st, pb, xm, m0, x1m, mk,
            xs2, xs1, hm0a, hm0b, mn0p, hx0a, hx0b, x0a, x0b,
            hm1a, hm1b, mn1p, hx1a, hx1b, x1a, x1b,
            hm2a, hm2b, mn2p, hx2a, hx2b, x2a, x2b);
        rowstep3<SRCF32>(imgF, imgH, outp, Rb + 3, gx0, st, pb, xm, m0, x1m, mk,
            xs3, xs2, hm0b, hm0a, mn0p, hx0b, hx0a, x0b, x0a,
            hm1b, hm1a, mn1p, hx1b, hx1a, x1b, x1a,
            hm2b, hm2a, mn2p, hx2b, hx2a, x2b, x2a);
    }
}

// partials layout: [z][16 tile slots][2];
// z<32: (sum clp*tgt, sum clp); z>=32: (sum skt*prd, sum skt)
__global__ __launch_bounds__(64) void finalize2(const float* __restrict__ partials,
                                                int ntiles,
                                                float* __restrict__ out) {
    const int b = threadIdx.x;
    float iflat = 0.f, tflat = 0.f;
    if (b < BB) {
        float v0 = 0.f, v1 = 0.f, v2 = 0.f, v3 = 0.f;
        for (int t = 0; t < ntiles; ++t) {
            v0 += partials[((size_t)b * 16 + t) * 2 + 0];
            v1 += partials[((size_t)b * 16 + t) * 2 + 1];
            v2 += partials[((size_t)(b + BB) * 16 + t) * 2 + 0];
            v3 += partials[((size_t)(b + BB) * 16 + t) * 2 + 1];
        }
        iflat = (v0 + 1e-6f) / (v1 + 1e-6f);
        tflat = (v2 + 1e-6f) / (v3 + 1e-6f);
    }
    float prod = iflat * tflat;
    float ssum = iflat + tflat;
    for (int off = 32; off; off >>= 1) {
        prod += __shfl_down(prod, off);
        ssum += __shfl_down(ssum, off);
    }
    if (threadIdx.x == 0) out[0] = 1.0f - 2.0f * prod / ssum;
}

extern "C" void kernel_launch(void* const* d_in, const int* in_sizes, int n_in,
                              void* d_out, int out_size, void* d_ws, size_t ws_size,
                              hipStream_t stream) {
    const float* pred = (const float*)d_in[0];
    const float* target = (const float*)d_in[1];
    float* out = (float*)d_out;
    char* ws = (char*)d_ws;
    const size_t N = (size_t)HH * WW;
    const size_t HALF = (size_t)BB * N;
    const size_t IMG16 = HALF * sizeof(unsigned short);

    dim3 block(64, 4);
    const int nby = HH / (CHUNK * 4);                   // 4
    const int ntiles = 2 * nby;                         // 8

    if (ws_size >= 4 * IMG16 + (1 << 16)) {
        // z=64: 10 iters = T3 -> T3 -> T2 -> T2fused  (4 passes)
        unsigned short* A = (unsigned short*)ws;
        unsigned short* B = (unsigned short*)(ws + 2 * IMG16);
        float* partials = (float*)(ws + 4 * IMG16);
        dim3 grid(2, nby, 2 * BB);
        skel3h<1><<<grid, block, 0, stream>>>(pred, target, nullptr, nullptr, A);
        skel3h<0><<<grid, block, 0, stream>>>(nullptr, nullptr, A, A + HALF, B);
        skel2h_t<0, 0><<<grid, block, 0, stream>>>(nullptr, nullptr, B, B + HALF,
                                                   nullptr, nullptr, A, nullptr);
        skel2h_t<0, 1><<<grid, block, 0, stream>>>(nullptr, nullptr, A, A + HALF,
                                                   target, pred, nullptr, partials);
        finalize2<<<1, 64, 0, stream>>>(partials, ntiles, out);
    } else {
        // fallback z=32: per-chain T3,T3,T2,T2fused
        unsigned short* b0 = (unsigned short*)ws;
        unsigned short* b1 = (unsigned short*)(ws + IMG16);
        float* partials = (float*)(ws + 2 * IMG16);
        dim3 grid(2, nby, BB);
        skel3h<1><<<grid, block, 0, stream>>>(pred, pred, nullptr, nullptr, b0);
        skel3h<0><<<grid, block, 0, stream>>>(nullptr, nullptr, b0, b0, b1);
        skel2h_t<0, 0><<<grid, block, 0, stream>>>(nullptr, nullptr, b1, b1,
                                                   nullptr, nullptr, b0, nullptr);
        skel2h_t<0, 1><<<grid, block, 0, stream>>>(nullptr, nullptr, b0, b0,
                                                   target, target, nullptr, partials);
        skel3h<1><<<grid, block, 0, stream>>>(target, target, nullptr, nullptr, b0);
        skel3h<0><<<grid, block, 0, stream>>>(nullptr, nullptr, b0, b0, b1);
        skel2h_t<0, 0><<<grid, block, 0, stream>>>(nullptr, nullptr, b1, b1,
                                                   nullptr, nullptr, b0, nullptr);
        skel2h_t<0, 1><<<grid, block, 0, stream>>>(nullptr, nullptr, b0, b0,
                                                   pred, pred, nullptr,
                                                   partials + (size_t)BB * 16 * 2);
        finalize2<<<1, 64, 0, stream>>>(partials, ntiles, out);
    }
}

// Round 20
// 141.470 us; speedup vs baseline: 1.6204x; 1.2062x over previous
//
#include <hip/hip_runtime.h>
#include <math.h>

#define HH 512
#define WW 512
#define BB 32
#define CHUNK 32

__device__ __forceinline__ float min3f(float a, float b, float c) {
    return fminf(fminf(a, b), c);
}
__device__ __forceinline__ float max3f(float a, float b, float c) {
    return fmaxf(fmaxf(a, b), c);
}
__device__ __forceinline__ float bf2f(unsigned short h) {
    return __uint_as_float((unsigned)h << 16);
}
__device__ __forceinline__ unsigned short f2bf(float f) {
    unsigned u = __float_as_uint(f);
    u += 0x7FFF + ((u >> 16) & 1);          // RNE; inputs are finite in [0,1]
    return (unsigned short)(u >> 16);
}

// Clamped 12-element row load (cols gx0-4..gx0+7), f32 or bf16 source.
// Row clamp wave-uniform SALU; column bases pre-clamped. Duplicating an
// in-window value never changes a min; only pad elements feeding non-masked
// min-pool outputs are xr[3] (lane s==0) / xr[8] (lane s==127).
template <int F32>
__device__ __forceinline__ void loadrow12(const float* __restrict__ imgF,
                                          const unsigned short* __restrict__ imgH,
                                          int R, int cm4, int c0, int cp4,
                                          bool isL, bool isR, float* xr) {
    const int Rc = R < 0 ? 0 : (R > HH - 1 ? HH - 1 : R);   // wave-uniform
    if (F32) {
        const float* rb = imgF + (size_t)Rc * WW;
        float4 v0 = *(const float4*)(rb + cm4);
        float4 v1 = *(const float4*)(rb + c0);
        float4 v2 = *(const float4*)(rb + cp4);
        xr[0] = v0.x; xr[1] = v0.y; xr[2] = v0.z; xr[3] = v0.w;
        xr[4] = v1.x; xr[5] = v1.y; xr[6] = v1.z; xr[7] = v1.w;
        xr[8] = v2.x; xr[9] = v2.y; xr[10] = v2.z; xr[11] = v2.w;
    } else {
        const unsigned short* rb = imgH + (size_t)Rc * WW;
        ushort4 v0 = *(const ushort4*)(rb + cm4);
        ushort4 v1 = *(const ushort4*)(rb + c0);
        ushort4 v2 = *(const ushort4*)(rb + cp4);
        xr[0] = bf2f(v0.x); xr[1] = bf2f(v0.y); xr[2] = bf2f(v0.z); xr[3] = bf2f(v0.w);
        xr[4] = bf2f(v1.x); xr[5] = bf2f(v1.y); xr[6] = bf2f(v1.z); xr[7] = bf2f(v1.w);
        xr[8] = bf2f(v2.x); xr[9] = bf2f(v2.y); xr[10] = bf2f(v2.z); xr[11] = bf2f(v2.w);
    }
    if (isL) xr[3] = xr[0];
    if (isR) xr[8] = xr[7];
}

// One row of the T=2 pipeline. Ring roles passed explicitly so a 4-row loop
// body needs ZERO cross-iteration copies (pairs alternate; load slots rotate
// period 4). All in-body "rotation copies" coalesce in SSA.
template <int SRCF32, int FUSED>
__device__ __forceinline__ void rowstep(
    const float* __restrict__ imgF, const unsigned short* __restrict__ imgH,
    const float* __restrict__ cmp, unsigned short* __restrict__ outp,
    float& acc0, float& acc1,
    int R, int cm4, int gx0, int cp4, bool isL, bool isR, bool doStore,
    float (&xA)[12], float (&xL)[12],
    float (&hm0o)[10], float (&hm0n)[10], float (&mn0p)[8],
    float (&hx0o)[8], float (&hx0n)[8],
    float (&x0o)[8], float (&x0n)[8],
    float (&hm1o)[6], float (&hm1n)[6], float (&mn1p)[4],
    float (&hx1o)[4], float (&hx1n)[4],
    float (&x1o)[4], float (&x1n)[4],
    float4& cqC, float4& cqL) {
    // prefetch row R+3 into xL (slot dead since last iteration)
    loadrow12<SRCF32>(imgF, imgH, R + 3, cm4, gx0, cp4, isL, isR, xL);

    float4 cmpCur;
    if (FUSED) {
        cmpCur = cqC;
        int Rc = R - 1;                                     // out-row consumed 3 steps later
        Rc = Rc < 0 ? 0 : (Rc > HH - 1 ? HH - 1 : Rc);      // wave-uniform clamp
        cqL = *(const float4*)(cmp + (size_t)Rc * WW + gx0);
    }

    // ---- iter1 horizontal min, row R ----
    float hm0c[10];
    #pragma unroll
    for (int i = 0; i < 10; ++i) hm0c[i] = min3f(xA[i], xA[i + 1], xA[i + 2]);

    // ---- iter1 min-pool row R-1 ----
    float mn0n[10];
    #pragma unroll
    for (int i = 0; i < 10; ++i) mn0n[i] = min3f(hm0o[i], hm0n[i], hm0c[i]);
    if (!((unsigned)(R - 1) < HH)) {            // wave-uniform, rarely taken
        #pragma unroll
        for (int i = 0; i < 10; ++i) mn0n[i] = -INFINITY;
    }
    if (isL) { mn0n[0] = -INFINITY; mn0n[1] = -INFINITY; mn0n[2] = -INFINITY; }
    if (isR) { mn0n[7] = -INFINITY; mn0n[8] = -INFINITY; mn0n[9] = -INFINITY; }

    // ---- horiz max of mn0 row R-1 ----
    float hx0c[8];
    #pragma unroll
    for (int j = 0; j < 8; ++j) hx0c[j] = max3f(mn0n[j], mn0n[j + 1], mn0n[j + 2]);

    // ---- iter1 update: x1 row R-2 ----
    float x1c[8];
    #pragma unroll
    for (int j = 0; j < 8; ++j) {
        float mp = max3f(hx0o[j], hx0n[j], hx0c[j]);
        float ct = fmaxf(mp - mn0p[j], 0.0f);
        x1c[j] = fmaxf(x0o[j] - ct, 0.0f);
    }
    if (!((unsigned)(R - 2) < HH)) {
        #pragma unroll
        for (int j = 0; j < 8; ++j) x1c[j] = INFINITY;
    }
    if (isL) { x1c[0] = INFINITY; x1c[1] = INFINITY; }
    if (isR) { x1c[6] = INFINITY; x1c[7] = INFINITY; }

    // rotate iter1 rings (coalesced in SSA)
    #pragma unroll
    for (int i = 0; i < 10; ++i) hm0o[i] = hm0c[i];
    #pragma unroll
    for (int j = 0; j < 8; ++j) { mn0p[j] = mn0n[j + 1]; hx0o[j] = hx0c[j]; x0o[j] = xA[j + 2]; }

    // ---- iter2 horizontal min, row R-2 ----
    float hm1c[6];
    #pragma unroll
    for (int k = 0; k < 6; ++k) hm1c[k] = min3f(x1c[k], x1c[k + 1], x1c[k + 2]);

    // ---- iter2 min-pool row R-3 ----
    float mn1n[6];
    #pragma unroll
    for (int k = 0; k < 6; ++k) mn1n[k] = min3f(hm1o[k], hm1n[k], hm1c[k]);
    if (!((unsigned)(R - 3) < HH)) {
        #pragma unroll
        for (int k = 0; k < 6; ++k) mn1n[k] = -INFINITY;
    }
    if (isL) mn1n[0] = -INFINITY;
    if (isR) mn1n[5] = -INFINITY;

    // ---- horiz max of mn1 row R-3 ----
    float hx1c[4];
    #pragma unroll
    for (int m = 0; m < 4; ++m) hx1c[m] = max3f(mn1n[m], mn1n[m + 1], mn1n[m + 2]);

    // ---- iter2 update: out row R-4 (wave-uniform branch) ----
    if (doStore) {
        float o[4];
        #pragma unroll
        for (int m = 0; m < 4; ++m) {
            float mp = max3f(hx1o[m], hx1n[m], hx1c[m]);
            float ct = fmaxf(mp - mn1p[m], 0.0f);
            o[m] = fmaxf(x1o[m] - ct, 0.0f);
        }
        if (FUSED) {
            acc0 += o[0] * cmpCur.x + o[1] * cmpCur.y + o[2] * cmpCur.z + o[3] * cmpCur.w;
            acc1 += o[0] + o[1] + o[2] + o[3];
        } else {
            ushort4 ov;
            ov.x = f2bf(o[0]); ov.y = f2bf(o[1]); ov.z = f2bf(o[2]); ov.w = f2bf(o[3]);
            *(ushort4*)(outp + (size_t)(R - 4) * WW + gx0) = ov;
        }
    }

    // rotate iter2 rings
    #pragma unroll
    for (int k = 0; k < 6; ++k) hm1o[k] = hm1c[k];
    #pragma unroll
    for (int m = 0; m < 4; ++m) { mn1p[m] = mn1n[m + 1]; hx1o[m] = hx1c[m]; x1o[m] = x1c[m + 2]; }
}

// Two fused soft-skeletonize iterations (T=2), bf16 intermediates, no LDS.
// Session-best configuration (round 12, 140.9 us): f32 compute + bf16
// storage; 4-row rotated loop body (I$-resident hot loop ~6-8KB, zero
// cross-iteration movs); CHUNK=32 (1.25x warm-up overhead, 512 blocks =
// exactly 2/CU); depth-3 load prefetch. Deeper fusion (T3/T4), packed-f16,
// shuffle-halo, and load batching all tested and falsified (rounds 13-19).
template <int SRCF32, int FUSED>
__global__ __launch_bounds__(256) void skel2b_t(const float* __restrict__ sfA,
                                                const float* __restrict__ sfB,
                                                const unsigned short* __restrict__ shA,
                                                const unsigned short* __restrict__ shB,
                                                const float* __restrict__ cmpA,
                                                const float* __restrict__ cmpB,
                                                unsigned short* __restrict__ dst,
                                                float* __restrict__ partials) {
    const int s = blockIdx.x * 64 + threadIdx.x;            // span 0..127
    const int y0 = (blockIdx.y * 4 + threadIdx.y) * CHUNK;  // output row start
    const int z = blockIdx.z;
    const float* imgF = nullptr;
    const unsigned short* imgH = nullptr;
    if (SRCF32) imgF = (z < BB) ? (sfA + (size_t)z * (HH * WW))
                                : (sfB + (size_t)(z - BB) * (HH * WW));
    else        imgH = (z < BB) ? (shA + (size_t)z * (HH * WW))
                                : (shB + (size_t)(z - BB) * (HH * WW));
    const float* cmp = nullptr;
    if (FUSED) cmp = (z < BB) ? (cmpA + (size_t)z * (HH * WW))
                              : (cmpB + (size_t)(z - BB) * (HH * WW));
    unsigned short* outp = FUSED ? nullptr : (dst + (size_t)z * (HH * WW));
    const int gx0 = 4 * s;
    const bool isL = (s == 0), isR = (s == 127);
    const int cm4 = isL ? 0 : gx0 - 4;
    const int cp4 = isR ? gx0 : gx0 + 4;

    // persistent ring state
    float hm0a[10], hm0b[10], mn0p[8];
    float hx0a[8], hx0b[8], x0a[8], x0b[8];
    float hm1a[6], hm1b[6], mn1p[4];
    float hx1a[4], hx1b[4], x1a[4], x1b[4];
    float xs0[12], xs1[12], xs2[12], xs3[12];
    float4 cq0, cq1, cq2, cq3;

    #pragma unroll
    for (int i = 0; i < 10; ++i) { hm0a[i] = INFINITY; hm0b[i] = INFINITY; }
    #pragma unroll
    for (int j = 0; j < 8; ++j)  { mn0p[j] = -INFINITY; hx0a[j] = -INFINITY; hx0b[j] = -INFINITY; x0a[j] = INFINITY; x0b[j] = INFINITY; }
    #pragma unroll
    for (int k = 0; k < 6; ++k)  { hm1a[k] = INFINITY; hm1b[k] = INFINITY; }
    #pragma unroll
    for (int m = 0; m < 4; ++m)  { mn1p[m] = -INFINITY; hx1a[m] = -INFINITY; hx1b[m] = -INFINITY; x1a[m] = INFINITY; x1b[m] = INFINITY; }
    cq0.x = cq0.y = cq0.z = cq0.w = 0.f;
    cq1 = cq0; cq2 = cq0; cq3 = cq0;

    float acc0 = 0.0f, acc1 = 0.0f;

    // prefetch rows y0-4 .. y0-2 into slots 0..2 (slot 3 loaded at step 0)
    loadrow12<SRCF32>(imgF, imgH, y0 - 4, cm4, gx0, cp4, isL, isR, xs0);
    loadrow12<SRCF32>(imgF, imgH, y0 - 3, cm4, gx0, cp4, isL, isR, xs1);
    loadrow12<SRCF32>(imgF, imgH, y0 - 2, cm4, gx0, cp4, isL, isR, xs2);

    #pragma unroll 1
    for (int it = 0; it < (CHUNK + 8) / 4; ++it) {
        const int Rb = y0 - 4 + 4 * it;
        const bool doStore = (it >= 2);
        rowstep<SRCF32, FUSED>(imgF, imgH, cmp, outp, acc0, acc1,
            Rb + 0, cm4, gx0, cp4, isL, isR, doStore,
            xs0, xs3, hm0a, hm0b, mn0p, hx0a, hx0b, x0a, x0b,
            hm1a, hm1b, mn1p, hx1a, hx1b, x1a, x1b, cq0, cq3);
        rowstep<SRCF32, FUSED>(imgF, imgH, cmp, outp, acc0, acc1,
            Rb + 1, cm4, gx0, cp4, isL, isR, doStore,
            xs1, xs0, hm0b, hm0a, mn0p, hx0b, hx0a, x0b, x0a,
            hm1b, hm1a, mn1p, hx1b, hx1a, x1b, x1a, cq1, cq0);
        rowstep<SRCF32, FUSED>(imgF, imgH, cmp, outp, acc0, acc1,
            Rb + 2, cm4, gx0, cp4, isL, isR, doStore,
            xs2, xs1, hm0a, hm0b, mn0p, hx0a, hx0b, x0a, x0b,
            hm1a, hm1b, mn1p, hx1a, hx1b, x1a, x1b, cq2, cq1);
        rowstep<SRCF32, FUSED>(imgF, imgH, cmp, outp, acc0, acc1,
            Rb + 3, cm4, gx0, cp4, isL, isR, doStore,
            xs3, xs2, hm0b, hm0a, mn0p, hx0b, hx0a, x0b, x0a,
            hm1b, hm1a, mn1p, hx1b, hx1a, x1b, x1a, cq3, cq2);
    }

    if (FUSED) {
        for (int off = 32; off; off >>= 1) {
            acc0 += __shfl_down(acc0, off);
            acc1 += __shfl_down(acc1, off);
        }
        __shared__ float red[4][2];
        if (threadIdx.x == 0) { red[threadIdx.y][0] = acc0; red[threadIdx.y][1] = acc1; }
        __syncthreads();
        if (threadIdx.x == 0 && threadIdx.y == 0) {
            const int tile = blockIdx.x * gridDim.y + blockIdx.y;  // 0..7
            float* p = partials + ((size_t)z * 16 + tile) * 2;
            p[0] = red[0][0] + red[1][0] + red[2][0] + red[3][0];
            p[1] = red[0][1] + red[1][1] + red[2][1] + red[3][1];
        }
    }
}

// partials layout: [z][16 tile slots][2] (first ntiles used per z);
// z<32: (sum clp*tgt, sum clp); z>=32: (sum skt*prd, sum skt)
__global__ __launch_bounds__(64) void finalize2(const float* __restrict__ partials,
                                                int ntiles,
                                                float* __restrict__ out) {
    const int b = threadIdx.x;
    float iflat = 0.f, tflat = 0.f;
    if (b < BB) {
        float v0 = 0.f, v1 = 0.f, v2 = 0.f, v3 = 0.f;
        for (int t = 0; t < ntiles; ++t) {
            v0 += partials[((size_t)b * 16 + t) * 2 + 0];
            v1 += partials[((size_t)b * 16 + t) * 2 + 1];
            v2 += partials[((size_t)(b + BB) * 16 + t) * 2 + 0];
            v3 += partials[((size_t)(b + BB) * 16 + t) * 2 + 1];
        }
        iflat = (v0 + 1e-6f) / (v1 + 1e-6f);
        tflat = (v2 + 1e-6f) / (v3 + 1e-6f);
    }
    float prod = iflat * tflat;
    float ssum = iflat + tflat;
    for (int off = 32; off; off >>= 1) {
        prod += __shfl_down(prod, off);
        ssum += __shfl_down(ssum, off);
    }
    if (threadIdx.x == 0) out[0] = 1.0f - 2.0f * prod / ssum;
}

extern "C" void kernel_launch(void* const* d_in, const int* in_sizes, int n_in,
                              void* d_out, int out_size, void* d_ws, size_t ws_size,
                              hipStream_t stream) {
    const float* pred = (const float*)d_in[0];
    const float* target = (const float*)d_in[1];
    float* out = (float*)d_out;
    char* ws = (char*)d_ws;
    const size_t N = (size_t)HH * WW;
    const size_t HALF = (size_t)BB * N;                 // elements per 32-image half
    const size_t IMG16 = HALF * sizeof(unsigned short); // 16 MB (bf16, 32 imgs)

    dim3 block(64, 4);
    const int nby = HH / (CHUNK * 4);                   // 4
    const int ntiles = 2 * nby;                         // 8

    if (ws_size >= 4 * IMG16 + (1 << 16)) {
        // z=64 path: both chains per dispatch; bf16 ping-pong A<->B (32MB each)
        unsigned short* A = (unsigned short*)ws;
        unsigned short* B = (unsigned short*)(ws + 2 * IMG16);
        float* partials = (float*)(ws + 4 * IMG16);     // 64*16*2 floats
        dim3 grid(2, nby, 2 * BB);
        skel2b_t<1, 0><<<grid, block, 0, stream>>>(pred, target, nullptr, nullptr,
                                                   nullptr, nullptr, A, nullptr);
        skel2b_t<0, 0><<<grid, block, 0, stream>>>(nullptr, nullptr, A, A + HALF,
                                                   nullptr, nullptr, B, nullptr);
        skel2b_t<0, 0><<<grid, block, 0, stream>>>(nullptr, nullptr, B, B + HALF,
                                                   nullptr, nullptr, A, nullptr);
        skel2b_t<0, 0><<<grid, block, 0, stream>>>(nullptr, nullptr, A, A + HALF,
                                                   nullptr, nullptr, B, nullptr);
        // final pass fused with reduction: z<32 companion=target, z>=32 companion=pred
        skel2b_t<0, 1><<<grid, block, 0, stream>>>(nullptr, nullptr, B, B + HALF,
                                                   target, pred, nullptr, partials);
        finalize2<<<1, 64, 0, stream>>>(partials, ntiles, out);
    } else {
        // fallback: z=32 path with 2x16MB bf16 buffers, per-chain passes
        unsigned short* b0 = (unsigned short*)ws;
        unsigned short* b1 = (unsigned short*)(ws + IMG16);
        float* partials = (float*)(ws + 2 * IMG16);
        dim3 grid(2, nby, BB);
        // pred chain
        skel2b_t<1, 0><<<grid, block, 0, stream>>>(pred, pred, nullptr, nullptr,
                                                   nullptr, nullptr, b0, nullptr);
        skel2b_t<0, 0><<<grid, block, 0, stream>>>(nullptr, nullptr, b0, b0,
                                                   nullptr, nullptr, b1, nullptr);
        skel2b_t<0, 0><<<grid, block, 0, stream>>>(nullptr, nullptr, b1, b1,
                                                   nullptr, nullptr, b0, nullptr);
        skel2b_t<0, 0><<<grid, block, 0, stream>>>(nullptr, nullptr, b0, b0,
                                                   nullptr, nullptr, b1, nullptr);
        skel2b_t<0, 1><<<grid, block, 0, stream>>>(nullptr, nullptr, b1, b1,
                                                   target, target, nullptr, partials);
        // target chain
        skel2b_t<1, 0><<<grid, block, 0, stream>>>(target, target, nullptr, nullptr,
                                                   nullptr, nullptr, b0, nullptr);
        skel2b_t<0, 0><<<grid, block, 0, stream>>>(nullptr, nullptr, b0, b0,
                                                   nullptr, nullptr, b1, nullptr);
        skel2b_t<0, 0><<<grid, block, 0, stream>>>(nullptr, nullptr, b1, b1,
                                                   nullptr, nullptr, b0, nullptr);
        skel2b_t<0, 0><<<grid, block, 0, stream>>>(nullptr, nullptr, b0, b0,
                                                   nullptr, nullptr, b1, nullptr);
        skel2b_t<0, 1><<<grid, block, 0, stream>>>(nullptr, nullptr, b1, b1,
                                                   pred, pred, nullptr,
                                                   partials + (size_t)BB * 16 * 2);
        finalize2<<<1, 64, 0, stream>>>(partials, ntiles, out);
    }
}